// Round 2
// baseline (292.467 us; speedup 1.0000x reference)
//
#include <hip/hip_runtime.h>
#include <hip/hip_bf16.h>
#include <math.h>

#define HH 128
#define NN 64
#define LL 4096
#define BB 8
#define NFFT 8192

__device__ __forceinline__ float2 cmul(float2 a, float2 b) {
    return make_float2(a.x * b.x - a.y * b.y, a.x * b.y + a.y * b.x);
}
__device__ __forceinline__ float2 cadd(float2 a, float2 b) {
    return make_float2(a.x + b.x, a.y + b.y);
}

// DIT radix-2: input bit-reversed, output natural order. sign=+1 => inverse (no 1/N scale).
template <int LOG2N>
__device__ void fft_dit(float2* d, int tid, int nthreads, float sign) {
    const int N = 1 << LOG2N;
#pragma unroll 1
    for (int s = 1; s <= LOG2N; ++s) {
        int half = 1 << (s - 1);
        float ang_base = sign * 6.28318530717958647692f / (float)(1 << s);
        for (int t = tid; t < (N >> 1); t += nthreads) {
            int j = t & (half - 1);
            int base = (t >> (s - 1)) << s;
            int i0 = base + j;
            int i1 = i0 + half;
            float sn, cs;
            sincosf(ang_base * (float)j, &sn, &cs);
            float2 a = d[i0];
            float2 b = d[i1];
            float2 wb = cmul(make_float2(cs, sn), b);
            d[i0] = make_float2(a.x + wb.x, a.y + wb.y);
            d[i1] = make_float2(a.x - wb.x, a.y - wb.y);
        }
        __syncthreads();
    }
}

// DIF radix-2: input natural order, output bit-reversed. sign=-1 => forward.
template <int LOG2N>
__device__ void fft_dif(float2* d, int tid, int nthreads, float sign) {
    const int N = 1 << LOG2N;
#pragma unroll 1
    for (int s = LOG2N; s >= 1; --s) {
        int half = 1 << (s - 1);
        float ang_base = sign * 6.28318530717958647692f / (float)(1 << s);
        for (int t = tid; t < (N >> 1); t += nthreads) {
            int j = t & (half - 1);
            int base = (t >> (s - 1)) << s;
            int i0 = base + j;
            int i1 = i0 + half;
            float2 a = d[i0];
            float2 b = d[i1];
            d[i0] = make_float2(a.x + b.x, a.y + b.y);
            float sn, cs;
            sincosf(ang_base * (float)j, &sn, &cs);
            d[i1] = cmul(make_float2(cs, sn), make_float2(a.x - b.x, a.y - b.y));
        }
        __syncthreads();
    }
}

// Kernel A: per h — Cauchy at_roots (into bit-rev slots) -> IFFT 4096 -> zero-pad -> DIF FFT 8192 -> Kf (bitrev order)
__global__ __launch_bounds__(512) void ssm_freq_kernel(
    const float* __restrict__ B_ri, const float* __restrict__ C_ri,
    const float* __restrict__ Lambda_ri, const float* __restrict__ P_ri,
    const float* __restrict__ step, float2* __restrict__ Kf) {
    __shared__ float2 sm[NFFT];  // 64 KB
    const int h = blockIdx.x;
    const int tid = threadIdx.x;

    // coefficient tables in the upper half (untouched by the 4096-point phase)
    float2* lam = sm + 4096;
    float2* v00 = sm + 4096 + 64;
    float2* v01 = sm + 4096 + 128;
    float2* v10 = sm + 4096 + 192;
    float2* v11 = sm + 4096 + 256;
    if (tid < NN) {
        int n = tid;
        float2 C = ((const float2*)C_ri)[h * NN + n];
        float2 Bv = ((const float2*)B_ri)[h * NN + n];
        float2 P = ((const float2*)P_ri)[h * NN + n];
        lam[n] = ((const float2*)Lambda_ri)[h * NN + n];
        float2 Cc = make_float2(C.x, -C.y);
        float2 Pc = make_float2(P.x, -P.y);
        v00[n] = cmul(Cc, Bv);
        v01[n] = cmul(Cc, P);
        v10[n] = cmul(Pc, Bv);
        v11[n] = cmul(Pc, P);
    }
    __syncthreads();

    const float two_over_step = 2.0f / step[0];
    for (int l = tid; l < LL; l += 512) {
        // z = exp(-2*pi*i*l/L)
        double th = -6.283185307179586476925286766559 * (double)l / (double)LL;
        float sn, cs;
        sincosf((float)th, &sn, &cs);
        float dr = 1.0f + cs, di = sn;          // 1+z
        float inv = 1.0f / (dr * dr + di * di);
        float nr = 1.0f - cs, ni = -sn;         // 1-z
        float gr = two_over_step * (nr * dr + ni * di) * inv;
        float gi = two_over_step * (ni * dr - nr * di) * inv;
        float2 cc = make_float2(2.0f * dr * inv, -2.0f * di * inv);  // 2/(1+z)

        float2 k00 = make_float2(0.f, 0.f), k01 = make_float2(0.f, 0.f);
        float2 k10 = make_float2(0.f, 0.f), k11 = make_float2(0.f, 0.f);
#pragma unroll 8
        for (int n = 0; n < NN; ++n) {
            float2 L_ = lam[n];
            float ar = gr - L_.x, ai = gi - L_.y;
            float id = 1.0f / (ar * ar + ai * ai);
            float2 r = make_float2(ar * id, -ai * id);  // 1/(g-lambda)
            k00 = cadd(k00, cmul(v00[n], r));
            k01 = cadd(k01, cmul(v01[n], r));
            k10 = cadd(k10, cmul(v10[n], r));
            k11 = cadd(k11, cmul(v11[n], r));
        }
        float wr = 1.0f + k11.x, wi = k11.y;
        float iw = 1.0f / (wr * wr + wi * wi);
        float2 winv = make_float2(wr * iw, -wi * iw);
        float2 t = cmul(cmul(k01, winv), k10);
        float2 at = cmul(cc, make_float2(k00.x - t.x, k00.y - t.y));
        sm[__brev((unsigned)l) >> (32 - 12)] = at;  // bit-reversed slot for DIT
    }
    __syncthreads();

    fft_dit<12>(sm, tid, 512, +1.0f);  // inverse FFT 4096, natural out (ends with sync)

    // kernel_time = real/4096; zero-pad to 8192
    for (int i = tid; i < 4096; i += 512) {
        sm[i] = make_float2(sm[i].x * (1.0f / 4096.0f), 0.0f);
        sm[i + 4096] = make_float2(0.f, 0.f);
    }
    __syncthreads();

    fft_dif<13>(sm, tid, 512, -1.0f);  // forward FFT 8192, bit-reversed out

    float2* kfp = Kf + (size_t)h * NFFT;
    for (int i = tid; i < NFFT; i += 512) kfp[i] = sm[i];
}

// Kernel B: transpose u [B,L,H] -> ut [B,H,L]
__global__ __launch_bounds__(256) void transpose_u_kernel(const float* __restrict__ u,
                                                          float* __restrict__ ut) {
    __shared__ float tile[32][33];
    int b = blockIdx.z;
    int h0 = blockIdx.x * 32, l0 = blockIdx.y * 32;
    const float* up = u + (size_t)b * LL * HH;
    float* utp = ut + (size_t)b * HH * LL;
    for (int i = threadIdx.y; i < 32; i += 8)
        tile[i][threadIdx.x] = up[(size_t)(l0 + i) * HH + h0 + threadIdx.x];
    __syncthreads();
    for (int i = threadIdx.y; i < 32; i += 8)
        utp[(size_t)(h0 + i) * LL + l0 + threadIdx.x] = tile[threadIdx.x][i];
}

// Kernel C: per (b,h) — FFT8192(u) * Kf -> IFFT -> yt [B,H,L]
__global__ __launch_bounds__(512) void conv_fft_kernel(const float* __restrict__ ut,
                                                       const float2* __restrict__ Kf,
                                                       float* __restrict__ yt) {
    __shared__ float2 sm[NFFT];  // 64 KB
    const int b = blockIdx.x >> 7;
    const int h = blockIdx.x & 127;
    const int tid = threadIdx.x;
    const float* up = ut + ((size_t)b * HH + h) * LL;
    for (int i = tid; i < 4096; i += 512) {
        sm[i] = make_float2(up[i], 0.f);
        sm[i + 4096] = make_float2(0.f, 0.f);
    }
    __syncthreads();
    fft_dif<13>(sm, tid, 512, -1.0f);  // forward, bitrev out (ends with sync)
    const float2* kfp = Kf + (size_t)h * NFFT;
    for (int i = tid; i < NFFT; i += 512) sm[i] = cmul(sm[i], kfp[i]);
    __syncthreads();
    fft_dit<13>(sm, tid, 512, +1.0f);  // inverse, natural out
    float* yp = yt + ((size_t)b * HH + h) * LL;
    for (int i = tid; i < 4096; i += 512) yp[i] = sm[i].x * (1.0f / (float)NFFT);
}

// Kernel S: skip[b,l] = sum_h u[b,l,h] * D[h]   (reference does u @ D with D:[H,1])
__global__ __launch_bounds__(256) void skip_kernel(const float* __restrict__ u,
                                                   const float* __restrict__ D,
                                                   float* __restrict__ skip) {
    int row = blockIdx.x * 2 + threadIdx.y;  // row = b*L + l, contiguous over [B*L)
    int tid = threadIdx.x;                   // 0..127
    float v = u[(size_t)row * HH + tid] * D[tid];
    for (int off = 32; off > 0; off >>= 1) v += __shfl_down(v, off, 64);
    __shared__ float partial[2][2];
    if ((tid & 63) == 0) partial[threadIdx.y][tid >> 6] = v;
    __syncthreads();
    if (tid == 0) skip[row] = partial[threadIdx.y][0] + partial[threadIdx.y][1];
}

// Kernel D: transpose yt [B,H,L] -> y [B,L,H], add broadcast skip[b,l]
__global__ __launch_bounds__(256) void transpose_y_kernel(const float* __restrict__ yt,
                                                          const float* __restrict__ skip,
                                                          float* __restrict__ y) {
    __shared__ float tile[32][33];
    int b = blockIdx.z;
    int h0 = blockIdx.x * 32, l0 = blockIdx.y * 32;
    const float* ytp = yt + (size_t)b * HH * LL;
    const float* skp = skip + (size_t)b * LL;
    float* yp = y + (size_t)b * LL * HH;
    for (int i = threadIdx.y; i < 32; i += 8)
        tile[i][threadIdx.x] = ytp[(size_t)(h0 + i) * LL + l0 + threadIdx.x];
    __syncthreads();
    for (int i = threadIdx.y; i < 32; i += 8) {
        size_t idx = (size_t)(l0 + i) * HH + h0 + threadIdx.x;
        yp[idx] = tile[threadIdx.x][i] + skp[l0 + i];
    }
}

extern "C" void kernel_launch(void* const* d_in, const int* in_sizes, int n_in,
                              void* d_out, int out_size, void* d_ws, size_t ws_size,
                              hipStream_t stream) {
    const float* u = (const float*)d_in[0];
    const float* B_ri = (const float*)d_in[1];
    const float* C_ri = (const float*)d_in[2];
    const float* D = (const float*)d_in[3];
    const float* Lambda_ri = (const float*)d_in[4];
    const float* P_ri = (const float*)d_in[5];
    const float* step = (const float*)d_in[6];
    float* out = (float*)d_out;

    char* ws = (char*)d_ws;
    float2* Kf = (float2*)ws;                                   // 128*8192*8  = 8 MB
    float* ut = (float*)(ws + (size_t)8 * 1024 * 1024);         // 16 MB
    float* yt = (float*)(ws + (size_t)24 * 1024 * 1024);        // 16 MB
    // skip reuses the ut region (ut is fully consumed by conv_fft_kernel before skip_kernel runs)
    float* skip = ut;                                           // 8*4096*4 = 128 KB

    ssm_freq_kernel<<<dim3(HH), dim3(512), 0, stream>>>(B_ri, C_ri, Lambda_ri, P_ri, step, Kf);
    transpose_u_kernel<<<dim3(HH / 32, LL / 32, BB), dim3(32, 8), 0, stream>>>(u, ut);
    conv_fft_kernel<<<dim3(BB * HH), dim3(512), 0, stream>>>(ut, Kf, yt);
    skip_kernel<<<dim3(BB * LL / 2), dim3(128, 2), 0, stream>>>(u, D, skip);
    transpose_y_kernel<<<dim3(HH / 32, LL / 32, BB), dim3(32, 8), 0, stream>>>(yt, skip, out);
}

// Round 3
// 193.587 us; speedup vs baseline: 1.5108x; 1.5108x over previous
//
#include <hip/hip_runtime.h>
#include <hip/hip_bf16.h>
#include <math.h>

#define HH 128
#define NN 64
#define LL 4096
#define BB 8
#define NFFT 8192

__device__ __forceinline__ float2 cmul(float2 a, float2 b) {
    return make_float2(a.x * b.x - a.y * b.y, a.x * b.y + a.y * b.x);
}
__device__ __forceinline__ float2 cadd(float2 a, float2 b) {
    return make_float2(a.x + b.x, a.y + b.y);
}
__device__ __forceinline__ int brev13(int x) { return (int)(__brev((unsigned)x) >> 19); }

// Twiddle via HW sin/cos: v_sin_f32/v_cos_f32 take REVOLUTIONS (sin(2*pi*x)).
// Butterfly args are exactly j/2^s revolutions in [0,0.5) -> no range reduction needed.
__device__ __forceinline__ float2 twiddle(float j, float inv2s, float sign) {
    float rev = j * inv2s;
    float cs = __builtin_amdgcn_cosf(rev);
    float sn = sign * __builtin_amdgcn_sinf(rev);
    return make_float2(cs, sn);
}

// DIT radix-2: input bit-reversed, output natural order. sign=+1 => inverse (no 1/N scale).
template <int LOG2N>
__device__ void fft_dit(float2* d, int tid, int nthreads, float sign) {
    const int N = 1 << LOG2N;
#pragma unroll 1
    for (int s = 1; s <= LOG2N; ++s) {
        int half = 1 << (s - 1);
        float inv2s = 1.0f / (float)(1 << s);
        for (int t = tid; t < (N >> 1); t += nthreads) {
            int j = t & (half - 1);
            int base = (t >> (s - 1)) << s;
            int i0 = base + j;
            int i1 = i0 + half;
            float2 w = twiddle((float)j, inv2s, sign);
            float2 a = d[i0];
            float2 b = d[i1];
            float2 wb = cmul(w, b);
            d[i0] = make_float2(a.x + wb.x, a.y + wb.y);
            d[i1] = make_float2(a.x - wb.x, a.y - wb.y);
        }
        __syncthreads();
    }
}

// DIF radix-2: input natural order, output bit-reversed. sign=-1 => forward.
template <int LOG2N>
__device__ void fft_dif(float2* d, int tid, int nthreads, float sign) {
    const int N = 1 << LOG2N;
#pragma unroll 1
    for (int s = LOG2N; s >= 1; --s) {
        int half = 1 << (s - 1);
        float inv2s = 1.0f / (float)(1 << s);
        for (int t = tid; t < (N >> 1); t += nthreads) {
            int j = t & (half - 1);
            int base = (t >> (s - 1)) << s;
            int i0 = base + j;
            int i1 = i0 + half;
            float2 a = d[i0];
            float2 b = d[i1];
            d[i0] = make_float2(a.x + b.x, a.y + b.y);
            float2 w = twiddle((float)j, inv2s, sign);
            d[i1] = cmul(w, make_float2(a.x - b.x, a.y - b.y));
        }
        __syncthreads();
    }
}

// Kernel A: per h — Cauchy at_roots (into bit-rev slots) -> IFFT 4096 -> zero-pad -> DIF FFT 8192 -> Kf (bitrev order)
__global__ __launch_bounds__(512) void ssm_freq_kernel(
    const float* __restrict__ B_ri, const float* __restrict__ C_ri,
    const float* __restrict__ Lambda_ri, const float* __restrict__ P_ri,
    const float* __restrict__ step, float2* __restrict__ Kf) {
    __shared__ float2 sm[NFFT];  // 64 KB
    const int h = blockIdx.x;
    const int tid = threadIdx.x;

    // coefficient tables in the upper half (untouched by the 4096-point phase)
    float2* lam = sm + 4096;
    float2* v00 = sm + 4096 + 64;
    float2* v01 = sm + 4096 + 128;
    float2* v10 = sm + 4096 + 192;
    float2* v11 = sm + 4096 + 256;
    if (tid < NN) {
        int n = tid;
        float2 C = ((const float2*)C_ri)[h * NN + n];
        float2 Bv = ((const float2*)B_ri)[h * NN + n];
        float2 P = ((const float2*)P_ri)[h * NN + n];
        lam[n] = ((const float2*)Lambda_ri)[h * NN + n];
        float2 Cc = make_float2(C.x, -C.y);
        float2 Pc = make_float2(P.x, -P.y);
        v00[n] = cmul(Cc, Bv);
        v01[n] = cmul(Cc, P);
        v10[n] = cmul(Pc, Bv);
        v11[n] = cmul(Pc, P);
    }
    __syncthreads();

    const float two_over_step = 2.0f / step[0];
    for (int l = tid; l < LL; l += 512) {
        // z = exp(-2*pi*i*l/L). Keep libm sincosf here: at l=2048 the fp32-pi
        // inexactness keeps 1+z away from exactly 0 (matches reference behavior).
        double th = -6.283185307179586476925286766559 * (double)l / (double)LL;
        float sn, cs;
        sincosf((float)th, &sn, &cs);
        float dr = 1.0f + cs, di = sn;          // 1+z
        float inv = 1.0f / (dr * dr + di * di);
        float nr = 1.0f - cs, ni = -sn;         // 1-z
        float gr = two_over_step * (nr * dr + ni * di) * inv;
        float gi = two_over_step * (ni * dr - nr * di) * inv;
        float2 cc = make_float2(2.0f * dr * inv, -2.0f * di * inv);  // 2/(1+z)

        float2 k00 = make_float2(0.f, 0.f), k01 = make_float2(0.f, 0.f);
        float2 k10 = make_float2(0.f, 0.f), k11 = make_float2(0.f, 0.f);
#pragma unroll 8
        for (int n = 0; n < NN; ++n) {
            float2 L_ = lam[n];
            float ar = gr - L_.x, ai = gi - L_.y;
            float id = 1.0f / (ar * ar + ai * ai);
            float2 r = make_float2(ar * id, -ai * id);  // 1/(g-lambda)
            k00 = cadd(k00, cmul(v00[n], r));
            k01 = cadd(k01, cmul(v01[n], r));
            k10 = cadd(k10, cmul(v10[n], r));
            k11 = cadd(k11, cmul(v11[n], r));
        }
        float wr = 1.0f + k11.x, wi = k11.y;
        float iw = 1.0f / (wr * wr + wi * wi);
        float2 winv = make_float2(wr * iw, -wi * iw);
        float2 t = cmul(cmul(k01, winv), k10);
        float2 at = cmul(cc, make_float2(k00.x - t.x, k00.y - t.y));
        sm[__brev((unsigned)l) >> (32 - 12)] = at;  // bit-reversed slot for DIT
    }
    __syncthreads();

    fft_dit<12>(sm, tid, 512, +1.0f);  // inverse FFT 4096, natural out (ends with sync)

    // kernel_time = real/4096; zero-pad to 8192
    for (int i = tid; i < 4096; i += 512) {
        sm[i] = make_float2(sm[i].x * (1.0f / 4096.0f), 0.0f);
        sm[i + 4096] = make_float2(0.f, 0.f);
    }
    __syncthreads();

    fft_dif<13>(sm, tid, 512, -1.0f);  // forward FFT 8192, bit-reversed out

    float2* kfp = Kf + (size_t)h * NFFT;
    for (int i = tid; i < NFFT; i += 512) kfp[i] = sm[i];
}

// Kernel B: transpose u [B,L,H] -> ut [B,H,L]
__global__ __launch_bounds__(256) void transpose_u_kernel(const float* __restrict__ u,
                                                          float* __restrict__ ut) {
    __shared__ float tile[32][33];
    int b = blockIdx.z;
    int h0 = blockIdx.x * 32, l0 = blockIdx.y * 32;
    const float* up = u + (size_t)b * LL * HH;
    float* utp = ut + (size_t)b * HH * LL;
    for (int i = threadIdx.y; i < 32; i += 8)
        tile[i][threadIdx.x] = up[(size_t)(l0 + i) * HH + h0 + threadIdx.x];
    __syncthreads();
    for (int i = threadIdx.y; i < 32; i += 8)
        utp[(size_t)(h0 + i) * LL + l0 + threadIdx.x] = tile[threadIdx.x][i];
}

// Kernel C: two-for-one — pack (h0,h1) as re+im, one fwd FFT, spectrum split,
// per-channel product with Kf, recombine, one inv FFT. Covers 2 channels/block.
__global__ __launch_bounds__(512) void conv_fft_kernel(const float* __restrict__ ut,
                                                       const float2* __restrict__ Kf,
                                                       float* __restrict__ yt) {
    __shared__ float2 sm[NFFT];  // 64 KB
    const int b = blockIdx.x >> 6;
    const int c = blockIdx.x & 63;
    const int h0 = 2 * c, h1 = 2 * c + 1;
    const int tid = threadIdx.x;
    const float* up0 = ut + ((size_t)b * HH + h0) * LL;
    const float* up1 = ut + ((size_t)b * HH + h1) * LL;
    for (int i = tid; i < 4096; i += 512) {
        sm[i] = make_float2(up0[i], up1[i]);
        sm[i + 4096] = make_float2(0.f, 0.f);
    }
    __syncthreads();
    fft_dif<13>(sm, tid, 512, -1.0f);  // forward, bitrev out (ends with sync)

    // Pointwise in bitrev order. Each thread-iteration exclusively owns the
    // conjugate pair (k, N-k) -> no cross-thread hazard, no sync in loop.
    // k-map swizzle (low6<->high6) spreads brev'd LDS addresses across banks.
    const float2* kf0 = Kf + (size_t)h0 * NFFT;
    const float2* kf1 = Kf + (size_t)h1 * NFFT;
    for (int t = tid; t <= 4096; t += 512) {
        int kk = (t < 4096) ? (((t & 63) << 6) | (t >> 6)) : 4096;
        bool self = (kk == 0) || (kk == 4096);
        int p = brev13(kk);
        int q = self ? p : brev13(NFFT - kk);
        float2 Zp = sm[p];
        float2 Zq = sm[q];
        float2 U0 = make_float2(0.5f * (Zp.x + Zq.x), 0.5f * (Zp.y - Zq.y));
        float2 U1 = make_float2(0.5f * (Zp.y + Zq.y), 0.5f * (Zq.x - Zp.x));
        float2 A = cmul(U0, kf0[p]);
        float2 C = cmul(U1, kf1[p]);
        sm[p] = make_float2(A.x - C.y, A.y + C.x);              // W[k]   = A + iC
        if (!self) sm[q] = make_float2(A.x + C.y, C.x - A.y);   // W[N-k] = conj(A - iC)
    }
    __syncthreads();

    fft_dit<13>(sm, tid, 512, +1.0f);  // inverse, natural out
    float* yp0 = yt + ((size_t)b * HH + h0) * LL;
    float* yp1 = yt + ((size_t)b * HH + h1) * LL;
    for (int i = tid; i < 4096; i += 512) {
        yp0[i] = sm[i].x * (1.0f / (float)NFFT);
        yp1[i] = sm[i].y * (1.0f / (float)NFFT);
    }
}

// Kernel S: skip[b,l] = sum_h u[b,l,h] * D[h]   (reference does u @ D with D:[H,1])
__global__ __launch_bounds__(256) void skip_kernel(const float* __restrict__ u,
                                                   const float* __restrict__ D,
                                                   float* __restrict__ skip) {
    int row = blockIdx.x * 2 + threadIdx.y;  // row = b*L + l, contiguous over [B*L)
    int tid = threadIdx.x;                   // 0..127
    float v = u[(size_t)row * HH + tid] * D[tid];
    for (int off = 32; off > 0; off >>= 1) v += __shfl_down(v, off, 64);
    __shared__ float partial[2][2];
    if ((tid & 63) == 0) partial[threadIdx.y][tid >> 6] = v;
    __syncthreads();
    if (tid == 0) skip[row] = partial[threadIdx.y][0] + partial[threadIdx.y][1];
}

// Kernel D: transpose yt [B,H,L] -> y [B,L,H], add broadcast skip[b,l]
__global__ __launch_bounds__(256) void transpose_y_kernel(const float* __restrict__ yt,
                                                          const float* __restrict__ skip,
                                                          float* __restrict__ y) {
    __shared__ float tile[32][33];
    int b = blockIdx.z;
    int h0 = blockIdx.x * 32, l0 = blockIdx.y * 32;
    const float* ytp = yt + (size_t)b * HH * LL;
    const float* skp = skip + (size_t)b * LL;
    float* yp = y + (size_t)b * LL * HH;
    for (int i = threadIdx.y; i < 32; i += 8)
        tile[i][threadIdx.x] = ytp[(size_t)(h0 + i) * LL + l0 + threadIdx.x];
    __syncthreads();
    for (int i = threadIdx.y; i < 32; i += 8) {
        size_t idx = (size_t)(l0 + i) * HH + h0 + threadIdx.x;
        yp[idx] = tile[threadIdx.x][i] + skp[l0 + i];
    }
}

extern "C" void kernel_launch(void* const* d_in, const int* in_sizes, int n_in,
                              void* d_out, int out_size, void* d_ws, size_t ws_size,
                              hipStream_t stream) {
    const float* u = (const float*)d_in[0];
    const float* B_ri = (const float*)d_in[1];
    const float* C_ri = (const float*)d_in[2];
    const float* D = (const float*)d_in[3];
    const float* Lambda_ri = (const float*)d_in[4];
    const float* P_ri = (const float*)d_in[5];
    const float* step = (const float*)d_in[6];
    float* out = (float*)d_out;

    char* ws = (char*)d_ws;
    float2* Kf = (float2*)ws;                                   // 128*8192*8  = 8 MB
    float* ut = (float*)(ws + (size_t)8 * 1024 * 1024);         // 16 MB
    float* yt = (float*)(ws + (size_t)24 * 1024 * 1024);        // 16 MB
    // skip reuses the ut region (ut is fully consumed by conv_fft_kernel before skip_kernel runs)
    float* skip = ut;                                           // 8*4096*4 = 128 KB

    ssm_freq_kernel<<<dim3(HH), dim3(512), 0, stream>>>(B_ri, C_ri, Lambda_ri, P_ri, step, Kf);
    transpose_u_kernel<<<dim3(HH / 32, LL / 32, BB), dim3(32, 8), 0, stream>>>(u, ut);
    conv_fft_kernel<<<dim3(BB * HH / 2), dim3(512), 0, stream>>>(ut, Kf, yt);
    skip_kernel<<<dim3(BB * LL / 2), dim3(128, 2), 0, stream>>>(u, D, skip);
    transpose_y_kernel<<<dim3(HH / 32, LL / 32, BB), dim3(32, 8), 0, stream>>>(yt, skip, out);
}

// Round 4
// 108.252 us; speedup vs baseline: 2.7017x; 1.7883x over previous
//
#include <hip/hip_runtime.h>
#include <hip/hip_bf16.h>
#include <math.h>

#define HH 128
#define NN 64
#define LL 4096
#define BB 8
#define NFFT 8192

__device__ __forceinline__ float2 cmul(float2 a, float2 b) {
    return make_float2(a.x * b.x - a.y * b.y, a.x * b.y + a.y * b.x);
}
__device__ __forceinline__ float2 cadd(float2 a, float2 b) {
    return make_float2(a.x + b.x, a.y + b.y);
}
__device__ __forceinline__ float2 csub(float2 a, float2 b) {
    return make_float2(a.x - b.x, a.y - b.y);
}
__device__ __forceinline__ int brev13(int x) { return (int)(__brev((unsigned)x) >> 19); }

// Twiddle via HW sin/cos (REVOLUTIONS, arg in [0,0.5) -> no range reduction).
__device__ __forceinline__ float2 twid(float rev, float sg) {
    return make_float2(__builtin_amdgcn_cosf(rev), sg * __builtin_amdgcn_sinf(rev));
}

// ---- Fused radix-4 passes (== two radix-2 stages; preserves bitrev semantics) ----

// DIF fused pair: stage half=2M then half=M. Input natural at pass entry.
template <int M>
__device__ __forceinline__ void dif_f4(float2* d, int N, int tid, int nt, float sg) {
    const float inv2m = 1.0f / (2.0f * (float)M);
    const float inv4m = 1.0f / (4.0f * (float)M);
    for (int q = tid; q < (N >> 2); q += nt) {
        int j = q & (M - 1);
        int i0 = ((q & ~(M - 1)) << 2) + j;
        float2 x0 = d[i0], x1 = d[i0 + M], x2 = d[i0 + 2 * M], x3 = d[i0 + 3 * M];
        float jf = (float)j;
        float2 wB = twid(jf * inv4m, sg);
        float2 wA = twid(jf * inv2m, sg);
        float2 a0 = cadd(x0, x2);
        float2 a2 = cmul(wB, csub(x0, x2));
        float2 a1 = cadd(x1, x3);
        float2 t = cmul(wB, csub(x1, x3));
        float2 a3 = make_float2(-sg * t.y, sg * t.x);  // (i*sg)*t
        d[i0] = cadd(a0, a1);
        d[i0 + M] = cmul(wA, csub(a0, a1));
        d[i0 + 2 * M] = cadd(a2, a3);
        d[i0 + 3 * M] = cmul(wA, csub(a2, a3));
    }
    __syncthreads();
}

// DIT fused pair: stage half=M then half=2M. Input bitrev at pass entry.
template <int M>
__device__ __forceinline__ void dit_f4(float2* d, int N, int tid, int nt, float sg) {
    const float inv2m = 1.0f / (2.0f * (float)M);
    const float inv4m = 1.0f / (4.0f * (float)M);
    for (int q = tid; q < (N >> 2); q += nt) {
        int j = q & (M - 1);
        int i0 = ((q & ~(M - 1)) << 2) + j;
        float2 x0 = d[i0], x1 = d[i0 + M], x2 = d[i0 + 2 * M], x3 = d[i0 + 3 * M];
        float jf = (float)j;
        float2 wA = twid(jf * inv2m, sg);
        float2 wB = twid(jf * inv4m, sg);
        float2 t0 = cmul(wA, x1), t1 = cmul(wA, x3);
        float2 a0 = cadd(x0, t0), a1 = csub(x0, t0);
        float2 a2 = cadd(x2, t1), a3 = csub(x2, t1);
        float2 u = cmul(wB, a2), v = cmul(wB, a3);
        float2 vi = make_float2(-sg * v.y, sg * v.x);  // (i*sg)*v
        d[i0] = cadd(a0, u);
        d[i0 + 2 * M] = csub(a0, u);
        d[i0 + M] = cadd(a1, vi);
        d[i0 + 3 * M] = csub(a1, vi);
    }
    __syncthreads();
}

// Leading radix-2 DIF stage (half = N/2) for odd log2N.
__device__ __forceinline__ void dif_r2_head(float2* d, int N, int tid, int nt, float sg) {
    int H = N >> 1;
    float invN = 1.0f / (float)N;
    for (int x = tid; x < H; x += nt) {
        float2 a = d[x], b = d[x + H];
        d[x] = cadd(a, b);
        float2 w = twid((float)x * invN, sg);
        d[x + H] = cmul(w, csub(a, b));
    }
    __syncthreads();
}

// Trailing radix-2 DIT stage (half = N/2) for odd log2N.
__device__ __forceinline__ void dit_r2_tail(float2* d, int N, int tid, int nt, float sg) {
    int H = N >> 1;
    float invN = 1.0f / (float)N;
    for (int x = tid; x < H; x += nt) {
        float2 w = twid((float)x * invN, sg);
        float2 a = d[x], b = cmul(w, d[x + H]);
        d[x] = cadd(a, b);
        d[x + H] = csub(a, b);
    }
    __syncthreads();
}

// Kernel A1: Cauchy at_roots[h][l] at full GPU width (natural order, coalesced).
__global__ __launch_bounds__(1024) void cauchy_kernel(
    const float* __restrict__ B_ri, const float* __restrict__ C_ri,
    const float* __restrict__ Lambda_ri, const float* __restrict__ P_ri,
    const float* __restrict__ step, float2* __restrict__ at_g) {
    __shared__ float2 lam[NN], v00[NN], v01[NN], v10[NN], v11[NN];
    const int h = blockIdx.y;
    const int tid = threadIdx.x;
    if (tid < NN) {
        int n = tid;
        float2 C = ((const float2*)C_ri)[h * NN + n];
        float2 Bv = ((const float2*)B_ri)[h * NN + n];
        float2 P = ((const float2*)P_ri)[h * NN + n];
        lam[n] = ((const float2*)Lambda_ri)[h * NN + n];
        float2 Cc = make_float2(C.x, -C.y);
        float2 Pc = make_float2(P.x, -P.y);
        v00[n] = cmul(Cc, Bv);
        v01[n] = cmul(Cc, P);
        v10[n] = cmul(Pc, Bv);
        v11[n] = cmul(Pc, P);
    }
    __syncthreads();

    const int l = blockIdx.x * 1024 + tid;
    const float two_over_step = 2.0f / step[0];
    // z = exp(-2*pi*i*l/L). libm sincosf here: at l=2048 the fp32-pi inexactness
    // keeps 1+z away from exactly 0 (matches reference behavior).
    double th = -6.283185307179586476925286766559 * (double)l / (double)LL;
    float sn, cs;
    sincosf((float)th, &sn, &cs);
    float dr = 1.0f + cs, di = sn;  // 1+z
    float inv = __builtin_amdgcn_rcpf(dr * dr + di * di);
    float nr = 1.0f - cs, ni = -sn;  // 1-z
    float gr = two_over_step * (nr * dr + ni * di) * inv;
    float gi = two_over_step * (ni * dr - nr * di) * inv;
    float2 cc = make_float2(2.0f * dr * inv, -2.0f * di * inv);  // 2/(1+z)

    float2 k00 = make_float2(0.f, 0.f), k01 = make_float2(0.f, 0.f);
    float2 k10 = make_float2(0.f, 0.f), k11 = make_float2(0.f, 0.f);
#pragma unroll 8
    for (int n = 0; n < NN; ++n) {
        float2 L_ = lam[n];
        float ar = gr - L_.x, ai = gi - L_.y;
        float id = __builtin_amdgcn_rcpf(ar * ar + ai * ai);
        float2 r = make_float2(ar * id, -ai * id);  // 1/(g-lambda)
        k00 = cadd(k00, cmul(v00[n], r));
        k01 = cadd(k01, cmul(v01[n], r));
        k10 = cadd(k10, cmul(v10[n], r));
        k11 = cadd(k11, cmul(v11[n], r));
    }
    float wr = 1.0f + k11.x, wi = k11.y;
    float iw = __builtin_amdgcn_rcpf(wr * wr + wi * wi);
    float2 winv = make_float2(wr * iw, -wi * iw);
    float2 t = cmul(cmul(k01, winv), k10);
    float2 at = cmul(cc, make_float2(k00.x - t.x, k00.y - t.y));
    at_g[(size_t)h * LL + l] = at;
}

// Kernel A2: per h — load at (swizzled, conflict-free bitrev LDS write) ->
// IFFT4096 -> scale/pad -> FFT8192 -> Kf (bitrev13 order).
__global__ __launch_bounds__(1024) void kfreq_kernel(const float2* __restrict__ at_g,
                                                     float2* __restrict__ Kf) {
    __shared__ float2 sm[NFFT];  // 64 KB
    const int h = blockIdx.x;
    const int tid = threadIdx.x;
    const float2* ap = at_g + (size_t)h * LL;
#pragma unroll
    for (int it = 0; it < 4; ++it) {
        int t = tid + it * 1024;
        int l = ((t & 63) << 6) | (t >> 6);          // low6<->high6 swap
        sm[__brev((unsigned)l) >> 20] = ap[l];       // LDS slot low bits vary per lane
    }
    __syncthreads();

    // inverse FFT 4096 (bitrev in -> natural out)
    dit_f4<1>(sm, 4096, tid, 1024, +1.f);
    dit_f4<4>(sm, 4096, tid, 1024, +1.f);
    dit_f4<16>(sm, 4096, tid, 1024, +1.f);
    dit_f4<64>(sm, 4096, tid, 1024, +1.f);
    dit_f4<256>(sm, 4096, tid, 1024, +1.f);
    dit_f4<1024>(sm, 4096, tid, 1024, +1.f);

    // kernel_time = real/4096; zero-pad to 8192
    for (int t = tid; t < 4096; t += 1024) {
        sm[t] = make_float2(sm[t].x * (1.0f / 4096.0f), 0.0f);
        sm[t + 4096] = make_float2(0.f, 0.f);
    }
    __syncthreads();

    // forward FFT 8192 (natural in -> bitrev13 out)
    dif_r2_head(sm, 8192, tid, 1024, -1.f);
    dif_f4<1024>(sm, 8192, tid, 1024, -1.f);
    dif_f4<256>(sm, 8192, tid, 1024, -1.f);
    dif_f4<64>(sm, 8192, tid, 1024, -1.f);
    dif_f4<16>(sm, 8192, tid, 1024, -1.f);
    dif_f4<4>(sm, 8192, tid, 1024, -1.f);
    dif_f4<1>(sm, 8192, tid, 1024, -1.f);

    float2* kfp = Kf + (size_t)h * NFFT;
    for (int i = tid; i < NFFT; i += 1024) kfp[i] = sm[i];
}

// Kernel B: transpose u [B,L,H] -> ut [B,H,L]
__global__ __launch_bounds__(256) void transpose_u_kernel(const float* __restrict__ u,
                                                          float* __restrict__ ut) {
    __shared__ float tile[32][33];
    int b = blockIdx.z;
    int h0 = blockIdx.x * 32, l0 = blockIdx.y * 32;
    const float* up = u + (size_t)b * LL * HH;
    float* utp = ut + (size_t)b * HH * LL;
    for (int i = threadIdx.y; i < 32; i += 8)
        tile[i][threadIdx.x] = up[(size_t)(l0 + i) * HH + h0 + threadIdx.x];
    __syncthreads();
    for (int i = threadIdx.y; i < 32; i += 8)
        utp[(size_t)(h0 + i) * LL + l0 + threadIdx.x] = tile[threadIdx.x][i];
}

// Kernel C: two-for-one conv — pack (h0,h1) as re+im, fwd FFT, spectrum split,
// per-channel product with Kf, recombine, inv FFT.
__global__ __launch_bounds__(512) void conv_fft_kernel(const float* __restrict__ ut,
                                                       const float2* __restrict__ Kf,
                                                       float* __restrict__ yt) {
    __shared__ float2 sm[NFFT];  // 64 KB
    const int b = blockIdx.x >> 6;
    const int c = blockIdx.x & 63;
    const int h0 = 2 * c, h1 = 2 * c + 1;
    const int tid = threadIdx.x;
    const float* up0 = ut + ((size_t)b * HH + h0) * LL;
    const float* up1 = ut + ((size_t)b * HH + h1) * LL;
    for (int i = tid; i < 4096; i += 512) {
        sm[i] = make_float2(up0[i], up1[i]);
        sm[i + 4096] = make_float2(0.f, 0.f);
    }
    __syncthreads();

    dif_r2_head(sm, 8192, tid, 512, -1.f);
    dif_f4<1024>(sm, 8192, tid, 512, -1.f);
    dif_f4<256>(sm, 8192, tid, 512, -1.f);
    dif_f4<64>(sm, 8192, tid, 512, -1.f);
    dif_f4<16>(sm, 8192, tid, 512, -1.f);
    dif_f4<4>(sm, 8192, tid, 512, -1.f);
    dif_f4<1>(sm, 8192, tid, 512, -1.f);

    // Pointwise in bitrev order; each thread-iteration owns conjugate pair (k, N-k).
    const float2* kf0 = Kf + (size_t)h0 * NFFT;
    const float2* kf1 = Kf + (size_t)h1 * NFFT;
    for (int t = tid; t <= 4096; t += 512) {
        int kk = (t < 4096) ? (((t & 63) << 6) | (t >> 6)) : 4096;
        bool self = (kk == 0) || (kk == 4096);
        int p = brev13(kk);
        int q = self ? p : brev13(NFFT - kk);
        float2 Zp = sm[p];
        float2 Zq = sm[q];
        float2 U0 = make_float2(0.5f * (Zp.x + Zq.x), 0.5f * (Zp.y - Zq.y));
        float2 U1 = make_float2(0.5f * (Zp.y + Zq.y), 0.5f * (Zq.x - Zp.x));
        float2 A = cmul(U0, kf0[p]);
        float2 C = cmul(U1, kf1[p]);
        sm[p] = make_float2(A.x - C.y, A.y + C.x);             // W[k]   = A + iC
        if (!self) sm[q] = make_float2(A.x + C.y, C.x - A.y);  // W[N-k] = conj(A - iC)
    }
    __syncthreads();

    dit_f4<1>(sm, 8192, tid, 512, +1.f);
    dit_f4<4>(sm, 8192, tid, 512, +1.f);
    dit_f4<16>(sm, 8192, tid, 512, +1.f);
    dit_f4<64>(sm, 8192, tid, 512, +1.f);
    dit_f4<256>(sm, 8192, tid, 512, +1.f);
    dit_f4<1024>(sm, 8192, tid, 512, +1.f);
    dit_r2_tail(sm, 8192, tid, 512, +1.f);

    float* yp0 = yt + ((size_t)b * HH + h0) * LL;
    float* yp1 = yt + ((size_t)b * HH + h1) * LL;
    for (int i = tid; i < 4096; i += 512) {
        yp0[i] = sm[i].x * (1.0f / (float)NFFT);
        yp1[i] = sm[i].y * (1.0f / (float)NFFT);
    }
}

// Kernel S: skip[b,l] = sum_h u[b,l,h] * D[h]
__global__ __launch_bounds__(256) void skip_kernel(const float* __restrict__ u,
                                                   const float* __restrict__ D,
                                                   float* __restrict__ skip) {
    int row = blockIdx.x * 2 + threadIdx.y;
    int tid = threadIdx.x;  // 0..127
    float v = u[(size_t)row * HH + tid] * D[tid];
    for (int off = 32; off > 0; off >>= 1) v += __shfl_down(v, off, 64);
    __shared__ float partial[2][2];
    if ((tid & 63) == 0) partial[threadIdx.y][tid >> 6] = v;
    __syncthreads();
    if (tid == 0) skip[row] = partial[threadIdx.y][0] + partial[threadIdx.y][1];
}

// Kernel D: transpose yt [B,H,L] -> y [B,L,H], add broadcast skip[b,l]
__global__ __launch_bounds__(256) void transpose_y_kernel(const float* __restrict__ yt,
                                                          const float* __restrict__ skip,
                                                          float* __restrict__ y) {
    __shared__ float tile[32][33];
    int b = blockIdx.z;
    int h0 = blockIdx.x * 32, l0 = blockIdx.y * 32;
    const float* ytp = yt + (size_t)b * HH * LL;
    const float* skp = skip + (size_t)b * LL;
    float* yp = y + (size_t)b * LL * HH;
    for (int i = threadIdx.y; i < 32; i += 8)
        tile[i][threadIdx.x] = ytp[(size_t)(h0 + i) * LL + l0 + threadIdx.x];
    __syncthreads();
    for (int i = threadIdx.y; i < 32; i += 8) {
        size_t idx = (size_t)(l0 + i) * HH + h0 + threadIdx.x;
        yp[idx] = tile[threadIdx.x][i] + skp[l0 + i];
    }
}

extern "C" void kernel_launch(void* const* d_in, const int* in_sizes, int n_in,
                              void* d_out, int out_size, void* d_ws, size_t ws_size,
                              hipStream_t stream) {
    const float* u = (const float*)d_in[0];
    const float* B_ri = (const float*)d_in[1];
    const float* C_ri = (const float*)d_in[2];
    const float* D = (const float*)d_in[3];
    const float* Lambda_ri = (const float*)d_in[4];
    const float* P_ri = (const float*)d_in[5];
    const float* step = (const float*)d_in[6];
    float* out = (float*)d_out;

    char* ws = (char*)d_ws;
    float2* Kf = (float2*)ws;                            // 8 MB @ 0
    float* ut = (float*)(ws + (size_t)8 * 1024 * 1024);  // 16 MB @ 8
    float* yt = (float*)(ws + (size_t)24 * 1024 * 1024); // 16 MB @ 24
    // at_g overlaps yt: consumed by kfreq before conv writes yt (stream-serial).
    float2* at_g = (float2*)yt;                          // 4 MB
    float* skip = ut;                                    // reused after conv reads ut

    cauchy_kernel<<<dim3(4, HH), dim3(1024), 0, stream>>>(B_ri, C_ri, Lambda_ri, P_ri, step, at_g);
    kfreq_kernel<<<dim3(HH), dim3(1024), 0, stream>>>(at_g, Kf);
    transpose_u_kernel<<<dim3(HH / 32, LL / 32, BB), dim3(32, 8), 0, stream>>>(u, ut);
    conv_fft_kernel<<<dim3(BB * HH / 2), dim3(512), 0, stream>>>(ut, Kf, yt);
    skip_kernel<<<dim3(BB * LL / 2), dim3(128, 2), 0, stream>>>(u, D, skip);
    transpose_y_kernel<<<dim3(HH / 32, LL / 32, BB), dim3(32, 8), 0, stream>>>(yt, skip, out);
}

// Round 5
// 107.040 us; speedup vs baseline: 2.7323x; 1.0113x over previous
//
#include <hip/hip_runtime.h>
#include <hip/hip_bf16.h>
#include <math.h>

#define HH 128
#define NN 64
#define LL 4096
#define BB 8
#define NFFT 8192
#define KSTR 4160  // per-h stride of permuted K spectrum (4097 used, padded)

__device__ __forceinline__ float2 cmul(float2 a, float2 b) {
    return make_float2(a.x * b.x - a.y * b.y, a.x * b.y + a.y * b.x);
}
__device__ __forceinline__ float2 cadd(float2 a, float2 b) {
    return make_float2(a.x + b.x, a.y + b.y);
}
__device__ __forceinline__ float2 csub(float2 a, float2 b) {
    return make_float2(a.x - b.x, a.y - b.y);
}
__device__ __forceinline__ int brev13(int x) { return (int)(__brev((unsigned)x) >> 19); }
// conv/kfreq shared frequency-index map (low6<->high6 swizzle, bank-friendly LDS)
__device__ __forceinline__ int kkmap(int t) {
    return (t < 4096) ? (((t & 63) << 6) | (t >> 6)) : 4096;
}

// Twiddle via HW sin/cos (REVOLUTIONS, arg in [0,0.5) -> no range reduction).
__device__ __forceinline__ float2 twid(float rev, float sg) {
    return make_float2(__builtin_amdgcn_cosf(rev), sg * __builtin_amdgcn_sinf(rev));
}

// ---- Fused radix-4 passes (== two radix-2 stages; preserves bitrev semantics) ----

// DIF fused pair: stage half=2M then half=M. Input natural at pass entry.
template <int M>
__device__ __forceinline__ void dif_f4(float2* d, int N, int tid, int nt, float sg) {
    const float inv2m = 1.0f / (2.0f * (float)M);
    const float inv4m = 1.0f / (4.0f * (float)M);
    for (int q = tid; q < (N >> 2); q += nt) {
        int j = q & (M - 1);
        int i0 = ((q & ~(M - 1)) << 2) + j;
        float2 x0 = d[i0], x1 = d[i0 + M], x2 = d[i0 + 2 * M], x3 = d[i0 + 3 * M];
        float jf = (float)j;
        float2 wB = twid(jf * inv4m, sg);
        float2 wA = twid(jf * inv2m, sg);
        float2 a0 = cadd(x0, x2);
        float2 a2 = cmul(wB, csub(x0, x2));
        float2 a1 = cadd(x1, x3);
        float2 t = cmul(wB, csub(x1, x3));
        float2 a3 = make_float2(-sg * t.y, sg * t.x);  // (i*sg)*t
        d[i0] = cadd(a0, a1);
        d[i0 + M] = cmul(wA, csub(a0, a1));
        d[i0 + 2 * M] = cadd(a2, a3);
        d[i0 + 3 * M] = cmul(wA, csub(a2, a3));
    }
    __syncthreads();
}

// DIT fused pair: stage half=M then half=2M. Input bitrev at pass entry.
template <int M>
__device__ __forceinline__ void dit_f4(float2* d, int N, int tid, int nt, float sg) {
    const float inv2m = 1.0f / (2.0f * (float)M);
    const float inv4m = 1.0f / (4.0f * (float)M);
    for (int q = tid; q < (N >> 2); q += nt) {
        int j = q & (M - 1);
        int i0 = ((q & ~(M - 1)) << 2) + j;
        float2 x0 = d[i0], x1 = d[i0 + M], x2 = d[i0 + 2 * M], x3 = d[i0 + 3 * M];
        float jf = (float)j;
        float2 wA = twid(jf * inv2m, sg);
        float2 wB = twid(jf * inv4m, sg);
        float2 t0 = cmul(wA, x1), t1 = cmul(wA, x3);
        float2 a0 = cadd(x0, t0), a1 = csub(x0, t0);
        float2 a2 = cadd(x2, t1), a3 = csub(x2, t1);
        float2 u = cmul(wB, a2), v = cmul(wB, a3);
        float2 vi = make_float2(-sg * v.y, sg * v.x);  // (i*sg)*v
        d[i0] = cadd(a0, u);
        d[i0 + 2 * M] = csub(a0, u);
        d[i0 + M] = cadd(a1, vi);
        d[i0 + 3 * M] = csub(a1, vi);
    }
    __syncthreads();
}

// Kernel A1: Cauchy at_roots[h][l] at full GPU width (natural order, coalesced).
__global__ __launch_bounds__(1024) void cauchy_kernel(
    const float* __restrict__ B_ri, const float* __restrict__ C_ri,
    const float* __restrict__ Lambda_ri, const float* __restrict__ P_ri,
    const float* __restrict__ step, float2* __restrict__ at_g) {
    __shared__ float2 lam[NN], v00[NN], v01[NN], v10[NN], v11[NN];
    const int h = blockIdx.y;
    const int tid = threadIdx.x;
    if (tid < NN) {
        int n = tid;
        float2 C = ((const float2*)C_ri)[h * NN + n];
        float2 Bv = ((const float2*)B_ri)[h * NN + n];
        float2 P = ((const float2*)P_ri)[h * NN + n];
        lam[n] = ((const float2*)Lambda_ri)[h * NN + n];
        float2 Cc = make_float2(C.x, -C.y);
        float2 Pc = make_float2(P.x, -P.y);
        v00[n] = cmul(Cc, Bv);
        v01[n] = cmul(Cc, P);
        v10[n] = cmul(Pc, Bv);
        v11[n] = cmul(Pc, P);
    }
    __syncthreads();

    const int l = blockIdx.x * 1024 + tid;
    const float two_over_step = 2.0f / step[0];
    // z = exp(-2*pi*i*l/L). libm sincosf: at l=2048 the fp32-pi inexactness
    // keeps 1+z away from exactly 0 (matches reference behavior).
    double th = -6.283185307179586476925286766559 * (double)l / (double)LL;
    float sn, cs;
    sincosf((float)th, &sn, &cs);
    float dr = 1.0f + cs, di = sn;  // 1+z
    float inv = __builtin_amdgcn_rcpf(dr * dr + di * di);
    float nr = 1.0f - cs, ni = -sn;  // 1-z
    float gr = two_over_step * (nr * dr + ni * di) * inv;
    float gi = two_over_step * (ni * dr - nr * di) * inv;
    float2 cc = make_float2(2.0f * dr * inv, -2.0f * di * inv);  // 2/(1+z)

    float2 k00 = make_float2(0.f, 0.f), k01 = make_float2(0.f, 0.f);
    float2 k10 = make_float2(0.f, 0.f), k11 = make_float2(0.f, 0.f);
#pragma unroll 8
    for (int n = 0; n < NN; ++n) {
        float2 L_ = lam[n];
        float ar = gr - L_.x, ai = gi - L_.y;
        float id = __builtin_amdgcn_rcpf(ar * ar + ai * ai);
        float2 r = make_float2(ar * id, -ai * id);  // 1/(g-lambda)
        k00 = cadd(k00, cmul(v00[n], r));
        k01 = cadd(k01, cmul(v01[n], r));
        k10 = cadd(k10, cmul(v10[n], r));
        k11 = cadd(k11, cmul(v11[n], r));
    }
    float wr = 1.0f + k11.x, wi = k11.y;
    float iw = __builtin_amdgcn_rcpf(wr * wr + wi * wi);
    float2 winv = make_float2(wr * iw, -wi * iw);
    float2 t = cmul(cmul(k01, winv), k10);
    float2 at = cmul(cc, make_float2(k00.x - t.x, k00.y - t.y));
    at_g[(size_t)h * LL + l] = at;
}

// Kernel A2: per h — scatter-load at -> IFFT4096 -> fused {scale + pad + head-r2}
// -> FFT8192 (remaining 12 stages) -> store permuted K spectrum KfP[h][t] = K_h(kk(t)).
__global__ __launch_bounds__(1024) void kfreq_kernel(const float2* __restrict__ at_g,
                                                     float2* __restrict__ KfP) {
    __shared__ float2 sm[NFFT];  // 64 KB
    const int h = blockIdx.x;
    const int tid = threadIdx.x;
    const float2* ap = at_g + (size_t)h * LL;
#pragma unroll
    for (int it = 0; it < 4; ++it) {
        int t = tid + it * 1024;
        int l = ((t & 63) << 6) | (t >> 6);     // low6<->high6 swap
        sm[__brev((unsigned)l) >> 20] = ap[l];  // LDS slot low bits vary per lane
    }
    __syncthreads();

    // inverse FFT 4096 (bitrev in -> natural out)
    dit_f4<1>(sm, 4096, tid, 1024, +1.f);
    dit_f4<4>(sm, 4096, tid, 1024, +1.f);
    dit_f4<16>(sm, 4096, tid, 1024, +1.f);
    dit_f4<64>(sm, 4096, tid, 1024, +1.f);
    dit_f4<256>(sm, 4096, tid, 1024, +1.f);
    dit_f4<1024>(sm, 4096, tid, 1024, +1.f);

    // fused: k = real/4096, zero-pad, and head radix-2 DIF stage (upper half = w*k)
    const float inv8192 = 1.0f / 8192.0f;
    for (int t = tid; t < 4096; t += 1024) {
        float kv = sm[t].x * (1.0f / 4096.0f);
        float2 w = twid((float)t * inv8192, -1.f);
        sm[t] = make_float2(kv, 0.f);
        sm[t + 4096] = make_float2(kv * w.x, kv * w.y);
    }
    __syncthreads();

    // forward FFT 8192, remaining stages (natural in -> bitrev13 out)
    dif_f4<1024>(sm, 8192, tid, 1024, -1.f);
    dif_f4<256>(sm, 8192, tid, 1024, -1.f);
    dif_f4<64>(sm, 8192, tid, 1024, -1.f);
    dif_f4<16>(sm, 8192, tid, 1024, -1.f);
    dif_f4<4>(sm, 8192, tid, 1024, -1.f);
    dif_f4<1>(sm, 8192, tid, 1024, -1.f);

    // permuted store: conv reads K linearly in t (coalesced); LDS gather is cheap here
    float2* kfp = KfP + (size_t)h * KSTR;
    for (int t = tid; t <= 4096; t += 1024) kfp[t] = sm[brev13(kkmap(t))];
}

// Kernel B: transpose u [B,L,H] -> ut [B,H,L]
__global__ __launch_bounds__(256) void transpose_u_kernel(const float* __restrict__ u,
                                                          float* __restrict__ ut) {
    __shared__ float tile[32][33];
    int b = blockIdx.z;
    int h0 = blockIdx.x * 32, l0 = blockIdx.y * 32;
    const float* up = u + (size_t)b * LL * HH;
    float* utp = ut + (size_t)b * HH * LL;
    for (int i = threadIdx.y; i < 32; i += 8)
        tile[i][threadIdx.x] = up[(size_t)(l0 + i) * HH + h0 + threadIdx.x];
    __syncthreads();
    for (int i = threadIdx.y; i < 32; i += 8)
        utp[(size_t)(h0 + i) * LL + l0 + threadIdx.x] = tile[threadIdx.x][i];
}

// Kernel C: two-for-one conv — pack (h0,h1) as re+im; fused {load + head-r2};
// fwd FFT (12 remaining stages); pointwise with coalesced permuted K; inv FFT
// (12 stages) with fused {tail-r2 + scale + store}.
__global__ __launch_bounds__(1024) void conv_fft_kernel(const float* __restrict__ ut,
                                                        const float2* __restrict__ KfP,
                                                        float* __restrict__ yt) {
    __shared__ float2 sm[NFFT];  // 64 KB
    const int b = blockIdx.x >> 6;
    const int c = blockIdx.x & 63;
    const int h0 = 2 * c, h1 = 2 * c + 1;
    const int tid = threadIdx.x;
    const float* up0 = ut + ((size_t)b * HH + h0) * LL;
    const float* up1 = ut + ((size_t)b * HH + h1) * LL;
    const float inv8192 = 1.0f / 8192.0f;

    // fused load + head radix-2 DIF stage (upper half of input is zero)
    for (int i = tid; i < 4096; i += 1024) {
        float2 a = make_float2(up0[i], up1[i]);
        float2 w = twid((float)i * inv8192, -1.f);
        sm[i] = a;
        sm[i + 4096] = cmul(w, a);
    }
    __syncthreads();

    dif_f4<1024>(sm, 8192, tid, 1024, -1.f);
    dif_f4<256>(sm, 8192, tid, 1024, -1.f);
    dif_f4<64>(sm, 8192, tid, 1024, -1.f);
    dif_f4<16>(sm, 8192, tid, 1024, -1.f);
    dif_f4<4>(sm, 8192, tid, 1024, -1.f);
    dif_f4<1>(sm, 8192, tid, 1024, -1.f);

    // Pointwise in bitrev order; each thread-iteration owns conjugate pair (k, N-k).
    // K reads are linear in t (coalesced); only K[p] is needed (Hermitian identity).
    const float2* kf0 = KfP + (size_t)h0 * KSTR;
    const float2* kf1 = KfP + (size_t)h1 * KSTR;
    for (int t = tid; t <= 4096; t += 1024) {
        int kk = kkmap(t);
        bool self = (kk == 0) || (kk == 4096);
        int p = brev13(kk);
        int q = self ? p : brev13(NFFT - kk);
        float2 K0 = kf0[t];
        float2 K1 = kf1[t];
        float2 Zp = sm[p];
        float2 Zq = sm[q];
        float2 U0 = make_float2(0.5f * (Zp.x + Zq.x), 0.5f * (Zp.y - Zq.y));
        float2 U1 = make_float2(0.5f * (Zp.y + Zq.y), 0.5f * (Zq.x - Zp.x));
        float2 A = cmul(U0, K0);
        float2 C = cmul(U1, K1);
        sm[p] = make_float2(A.x - C.y, A.y + C.x);             // W[k]   = A + iC
        if (!self) sm[q] = make_float2(A.x + C.y, C.x - A.y);  // W[N-k] = conj(A - iC)
    }
    __syncthreads();

    dit_f4<1>(sm, 8192, tid, 1024, +1.f);
    dit_f4<4>(sm, 8192, tid, 1024, +1.f);
    dit_f4<16>(sm, 8192, tid, 1024, +1.f);
    dit_f4<64>(sm, 8192, tid, 1024, +1.f);
    dit_f4<256>(sm, 8192, tid, 1024, +1.f);
    dit_f4<1024>(sm, 8192, tid, 1024, +1.f);

    // fused tail radix-2 DIT stage + 1/N scale + store (only first 4096 samples kept)
    float* yp0 = yt + ((size_t)b * HH + h0) * LL;
    float* yp1 = yt + ((size_t)b * HH + h1) * LL;
    const float invN = 1.0f / (float)NFFT;
    for (int x = tid; x < 4096; x += 1024) {
        float2 w = twid((float)x * inv8192, +1.f);
        float2 a = sm[x];
        float2 bb = cmul(w, sm[x + 4096]);
        yp0[x] = (a.x + bb.x) * invN;
        yp1[x] = (a.y + bb.y) * invN;
    }
}

// Kernel S: skip[b,l] = sum_h u[b,l,h] * D[h]
__global__ __launch_bounds__(256) void skip_kernel(const float* __restrict__ u,
                                                   const float* __restrict__ D,
                                                   float* __restrict__ skip) {
    int row = blockIdx.x * 2 + threadIdx.y;
    int tid = threadIdx.x;  // 0..127
    float v = u[(size_t)row * HH + tid] * D[tid];
    for (int off = 32; off > 0; off >>= 1) v += __shfl_down(v, off, 64);
    __shared__ float partial[2][2];
    if ((tid & 63) == 0) partial[threadIdx.y][tid >> 6] = v;
    __syncthreads();
    if (tid == 0) skip[row] = partial[threadIdx.y][0] + partial[threadIdx.y][1];
}

// Kernel D: transpose yt [B,H,L] -> y [B,L,H], add broadcast skip[b,l]
__global__ __launch_bounds__(256) void transpose_y_kernel(const float* __restrict__ yt,
                                                          const float* __restrict__ skip,
                                                          float* __restrict__ y) {
    __shared__ float tile[32][33];
    int b = blockIdx.z;
    int h0 = blockIdx.x * 32, l0 = blockIdx.y * 32;
    const float* ytp = yt + (size_t)b * HH * LL;
    const float* skp = skip + (size_t)b * LL;
    float* yp = y + (size_t)b * LL * HH;
    for (int i = threadIdx.y; i < 32; i += 8)
        tile[i][threadIdx.x] = ytp[(size_t)(h0 + i) * LL + l0 + threadIdx.x];
    __syncthreads();
    for (int i = threadIdx.y; i < 32; i += 8) {
        size_t idx = (size_t)(l0 + i) * HH + h0 + threadIdx.x;
        yp[idx] = tile[threadIdx.x][i] + skp[l0 + i];
    }
}

extern "C" void kernel_launch(void* const* d_in, const int* in_sizes, int n_in,
                              void* d_out, int out_size, void* d_ws, size_t ws_size,
                              hipStream_t stream) {
    const float* u = (const float*)d_in[0];
    const float* B_ri = (const float*)d_in[1];
    const float* C_ri = (const float*)d_in[2];
    const float* D = (const float*)d_in[3];
    const float* Lambda_ri = (const float*)d_in[4];
    const float* P_ri = (const float*)d_in[5];
    const float* step = (const float*)d_in[6];
    float* out = (float*)d_out;

    char* ws = (char*)d_ws;
    float2* KfP = (float2*)ws;                            // 128*4160*8 ≈ 4.1 MB @ 0
    float* ut = (float*)(ws + (size_t)8 * 1024 * 1024);   // 16 MB @ 8
    float* yt = (float*)(ws + (size_t)24 * 1024 * 1024);  // 16 MB @ 24
    // at_g overlaps yt: consumed by kfreq before conv writes yt (stream-serial).
    float2* at_g = (float2*)yt;                           // 4 MB
    float* skip = ut;                                     // reused after conv reads ut

    cauchy_kernel<<<dim3(4, HH), dim3(1024), 0, stream>>>(B_ri, C_ri, Lambda_ri, P_ri, step, at_g);
    kfreq_kernel<<<dim3(HH), dim3(1024), 0, stream>>>(at_g, KfP);
    transpose_u_kernel<<<dim3(HH / 32, LL / 32, BB), dim3(32, 8), 0, stream>>>(u, ut);
    conv_fft_kernel<<<dim3(BB * HH / 2), dim3(1024), 0, stream>>>(ut, KfP, yt);
    skip_kernel<<<dim3(BB * LL / 2), dim3(128, 2), 0, stream>>>(u, D, skip);
    transpose_y_kernel<<<dim3(HH / 32, LL / 32, BB), dim3(32, 8), 0, stream>>>(yt, skip, out);
}

// Round 6
// 93.556 us; speedup vs baseline: 3.1261x; 1.1441x over previous
//
#include <hip/hip_runtime.h>
#include <hip/hip_bf16.h>
#include <math.h>

#define HH 128
#define NN 64
#define LL 4096
#define BB 8
#define NFFT 8192
#define KSTR 4160  // per-h stride of permuted K spectrum (4097 used, padded)

// stage1 grid partitions (order matters: cauchy first = critical path for kfreq)
#define CAU_BLOCKS 2048   // 128 h x 16 l-blocks of 256
#define TRU_BLOCKS 4096   // 8 b x 4 h-tiles x 128 l-tiles (32x32)
#define SKP_BLOCKS 8192   // 4 rows/block (1 row per 64-lane wave)

__device__ __forceinline__ float2 cmul(float2 a, float2 b) {
    return make_float2(a.x * b.x - a.y * b.y, a.x * b.y + a.y * b.x);
}
__device__ __forceinline__ float2 cadd(float2 a, float2 b) {
    return make_float2(a.x + b.x, a.y + b.y);
}
__device__ __forceinline__ float2 csub(float2 a, float2 b) {
    return make_float2(a.x - b.x, a.y - b.y);
}
__device__ __forceinline__ int brev13(int x) { return (int)(__brev((unsigned)x) >> 19); }
// conv/kfreq shared frequency-index map (low6<->high6 swizzle, bank-friendly LDS)
__device__ __forceinline__ int kkmap(int t) {
    return (t < 4096) ? (((t & 63) << 6) | (t >> 6)) : 4096;
}

// Twiddle via HW sin/cos (REVOLUTIONS, arg in [0,0.5) -> no range reduction).
__device__ __forceinline__ float2 twid(float rev, float sg) {
    return make_float2(__builtin_amdgcn_cosf(rev), sg * __builtin_amdgcn_sinf(rev));
}

// ---- Fused radix-4 passes (== two radix-2 stages; preserves bitrev semantics) ----

// DIF fused pair: stage half=2M then half=M. Input natural at pass entry.
template <int M>
__device__ __forceinline__ void dif_f4(float2* d, int N, int tid, int nt, float sg) {
    const float inv2m = 1.0f / (2.0f * (float)M);
    const float inv4m = 1.0f / (4.0f * (float)M);
    for (int q = tid; q < (N >> 2); q += nt) {
        int j = q & (M - 1);
        int i0 = ((q & ~(M - 1)) << 2) + j;
        float2 x0 = d[i0], x1 = d[i0 + M], x2 = d[i0 + 2 * M], x3 = d[i0 + 3 * M];
        float jf = (float)j;
        float2 wB = twid(jf * inv4m, sg);
        float2 wA = twid(jf * inv2m, sg);
        float2 a0 = cadd(x0, x2);
        float2 a2 = cmul(wB, csub(x0, x2));
        float2 a1 = cadd(x1, x3);
        float2 t = cmul(wB, csub(x1, x3));
        float2 a3 = make_float2(-sg * t.y, sg * t.x);  // (i*sg)*t
        d[i0] = cadd(a0, a1);
        d[i0 + M] = cmul(wA, csub(a0, a1));
        d[i0 + 2 * M] = cadd(a2, a3);
        d[i0 + 3 * M] = cmul(wA, csub(a2, a3));
    }
    __syncthreads();
}

// DIT fused pair: stage half=M then half=2M. Input bitrev at pass entry.
template <int M>
__device__ __forceinline__ void dit_f4(float2* d, int N, int tid, int nt, float sg) {
    const float inv2m = 1.0f / (2.0f * (float)M);
    const float inv4m = 1.0f / (4.0f * (float)M);
    for (int q = tid; q < (N >> 2); q += nt) {
        int j = q & (M - 1);
        int i0 = ((q & ~(M - 1)) << 2) + j;
        float2 x0 = d[i0], x1 = d[i0 + M], x2 = d[i0 + 2 * M], x3 = d[i0 + 3 * M];
        float jf = (float)j;
        float2 wA = twid(jf * inv2m, sg);
        float2 wB = twid(jf * inv4m, sg);
        float2 t0 = cmul(wA, x1), t1 = cmul(wA, x3);
        float2 a0 = cadd(x0, t0), a1 = csub(x0, t0);
        float2 a2 = cadd(x2, t1), a3 = csub(x2, t1);
        float2 u = cmul(wB, a2), v = cmul(wB, a3);
        float2 vi = make_float2(-sg * v.y, sg * v.x);  // (i*sg)*v
        d[i0] = cadd(a0, u);
        d[i0 + 2 * M] = csub(a0, u);
        d[i0 + M] = cadd(a1, vi);
        d[i0 + 3 * M] = csub(a1, vi);
    }
    __syncthreads();
}

// Stage 1 (fused): [cauchy at_roots] ++ [transpose u->ut] ++ [skip = u@D].
// The three partitions are data-independent; cauchy (VALU-bound) overlaps the
// memory-bound transpose/skip blocks on the same CUs.
__global__ __launch_bounds__(256) void stage1_kernel(
    const float* __restrict__ u,
    const float* __restrict__ B_ri, const float* __restrict__ C_ri,
    const float* __restrict__ D,
    const float* __restrict__ Lambda_ri, const float* __restrict__ P_ri,
    const float* __restrict__ step,
    float2* __restrict__ at_g, float* __restrict__ ut, float* __restrict__ skip) {
    __shared__ float4 smem[272];  // union: cauchy tables 2560B / transpose tile 4224B
    const int bid = blockIdx.x;
    const int tid = threadIdx.x;

    if (bid < CAU_BLOCKS) {
        // ---- Cauchy partition: h = bid>>4, l = (bid&15)*256 + tid ----
        float4* tabA = smem;                    // [64]: lam.re, lam.im, v00.re, v00.im
        float4* tabB = smem + 64;               // [64]: v01.re, v01.im, v10.re, v10.im
        float2* tabC = (float2*)(smem + 128);   // [64]: v11
        const int h = bid >> 4;
        if (tid < NN) {
            int n = tid;
            float2 C = ((const float2*)C_ri)[h * NN + n];
            float2 Bv = ((const float2*)B_ri)[h * NN + n];
            float2 P = ((const float2*)P_ri)[h * NN + n];
            float2 lam = ((const float2*)Lambda_ri)[h * NN + n];
            float2 Cc = make_float2(C.x, -C.y);
            float2 Pc = make_float2(P.x, -P.y);
            float2 v00 = cmul(Cc, Bv);
            float2 v01 = cmul(Cc, P);
            float2 v10 = cmul(Pc, Bv);
            float2 v11 = cmul(Pc, P);
            tabA[n] = make_float4(lam.x, lam.y, v00.x, v00.y);
            tabB[n] = make_float4(v01.x, v01.y, v10.x, v10.y);
            tabC[n] = v11;
        }
        __syncthreads();

        const int l = ((bid & 15) << 8) | tid;
        const float two_over_step = 2.0f / step[0];
        // z = exp(-2*pi*i*l/L). libm sincosf: at l=2048 the fp32-pi inexactness
        // keeps 1+z away from exactly 0 (matches reference behavior).
        double th = -6.283185307179586476925286766559 * (double)l / (double)LL;
        float sn, cs;
        sincosf((float)th, &sn, &cs);
        float dr = 1.0f + cs, di = sn;  // 1+z
        float inv = __builtin_amdgcn_rcpf(dr * dr + di * di);
        float nr = 1.0f - cs, ni = -sn;  // 1-z
        float gr = two_over_step * (nr * dr + ni * di) * inv;
        float gi = two_over_step * (ni * dr - nr * di) * inv;
        float2 cc = make_float2(2.0f * dr * inv, -2.0f * di * inv);  // 2/(1+z)

        float2 k00 = make_float2(0.f, 0.f), k01 = make_float2(0.f, 0.f);
        float2 k10 = make_float2(0.f, 0.f), k11 = make_float2(0.f, 0.f);
#pragma unroll 8
        for (int n = 0; n < NN; ++n) {
            float4 tA = tabA[n];
            float4 tB = tabB[n];
            float2 tC = tabC[n];
            float ar = gr - tA.x, ai = gi - tA.y;
            float id = __builtin_amdgcn_rcpf(ar * ar + ai * ai);
            float2 r = make_float2(ar * id, -ai * id);  // 1/(g-lambda)
            k00 = cadd(k00, cmul(make_float2(tA.z, tA.w), r));
            k01 = cadd(k01, cmul(make_float2(tB.x, tB.y), r));
            k10 = cadd(k10, cmul(make_float2(tB.z, tB.w), r));
            k11 = cadd(k11, cmul(tC, r));
        }
        float wr = 1.0f + k11.x, wi = k11.y;
        float iw = __builtin_amdgcn_rcpf(wr * wr + wi * wi);
        float2 winv = make_float2(wr * iw, -wi * iw);
        float2 t = cmul(cmul(k01, winv), k10);
        float2 at = cmul(cc, make_float2(k00.x - t.x, k00.y - t.y));
        at_g[(size_t)h * LL + l] = at;
    } else if (bid < CAU_BLOCKS + TRU_BLOCKS) {
        // ---- Transpose partition: u [B,L,H] -> ut [B,H,L], 32x32 tiles ----
        float* tile = (float*)smem;  // [32][33]
        int tb = bid - CAU_BLOCKS;
        int b = tb >> 9;
        int h0 = ((tb >> 7) & 3) * 32;
        int l0 = (tb & 127) * 32;
        int tx = tid & 31, ty = tid >> 5;  // ty 0..7
        const float* up = u + (size_t)b * LL * HH;
        float* utp = ut + (size_t)b * HH * LL;
        for (int i = ty; i < 32; i += 8)
            tile[i * 33 + tx] = up[(size_t)(l0 + i) * HH + h0 + tx];
        __syncthreads();
        for (int i = ty; i < 32; i += 8)
            utp[(size_t)(h0 + i) * LL + l0 + tx] = tile[tx * 33 + i];
    } else {
        // ---- Skip partition: skip[row] = sum_h u[row,h]*D[h]; 1 row per wave ----
        int sb = bid - (CAU_BLOCKS + TRU_BLOCKS);
        int wid = tid >> 6, lane = tid & 63;
        int row = sb * 4 + wid;
        const float* ur = u + (size_t)row * HH;
        float v = ur[lane] * D[lane] + ur[lane + 64] * D[lane + 64];
        for (int off = 32; off > 0; off >>= 1) v += __shfl_down(v, off, 64);
        if (lane == 0) skip[row] = v;
    }
}

// Kernel A2: per h — scatter-load at -> IFFT4096 -> fused {scale + pad + head-r2}
// -> FFT8192 (remaining 12 stages) -> store permuted K spectrum KfP[h][t] = K_h(kk(t)).
__global__ __launch_bounds__(1024) void kfreq_kernel(const float2* __restrict__ at_g,
                                                     float2* __restrict__ KfP) {
    __shared__ float2 sm[NFFT];  // 64 KB
    const int h = blockIdx.x;
    const int tid = threadIdx.x;
    const float2* ap = at_g + (size_t)h * LL;
#pragma unroll
    for (int it = 0; it < 4; ++it) {
        int t = tid + it * 1024;
        int l = ((t & 63) << 6) | (t >> 6);     // low6<->high6 swap
        sm[__brev((unsigned)l) >> 20] = ap[l];  // LDS slot low bits vary per lane
    }
    __syncthreads();

    // inverse FFT 4096 (bitrev in -> natural out)
    dit_f4<1>(sm, 4096, tid, 1024, +1.f);
    dit_f4<4>(sm, 4096, tid, 1024, +1.f);
    dit_f4<16>(sm, 4096, tid, 1024, +1.f);
    dit_f4<64>(sm, 4096, tid, 1024, +1.f);
    dit_f4<256>(sm, 4096, tid, 1024, +1.f);
    dit_f4<1024>(sm, 4096, tid, 1024, +1.f);

    // fused: k = real/4096, zero-pad, and head radix-2 DIF stage (upper half = w*k)
    const float inv8192 = 1.0f / 8192.0f;
    for (int t = tid; t < 4096; t += 1024) {
        float kv = sm[t].x * (1.0f / 4096.0f);
        float2 w = twid((float)t * inv8192, -1.f);
        sm[t] = make_float2(kv, 0.f);
        sm[t + 4096] = make_float2(kv * w.x, kv * w.y);
    }
    __syncthreads();

    // forward FFT 8192, remaining stages (natural in -> bitrev13 out)
    dif_f4<1024>(sm, 8192, tid, 1024, -1.f);
    dif_f4<256>(sm, 8192, tid, 1024, -1.f);
    dif_f4<64>(sm, 8192, tid, 1024, -1.f);
    dif_f4<16>(sm, 8192, tid, 1024, -1.f);
    dif_f4<4>(sm, 8192, tid, 1024, -1.f);
    dif_f4<1>(sm, 8192, tid, 1024, -1.f);

    // permuted store: conv reads K linearly in t (coalesced); LDS gather is cheap here
    float2* kfp = KfP + (size_t)h * KSTR;
    for (int t = tid; t <= 4096; t += 1024) kfp[t] = sm[brev13(kkmap(t))];
}

// Kernel C: two-for-one conv — pack (h0,h1) as re+im; fused {load + head-r2};
// fwd FFT (12 remaining stages); pointwise with coalesced permuted K; inv FFT
// (12 stages) with fused {tail-r2 + scale + store}.
__global__ __launch_bounds__(1024) void conv_fft_kernel(const float* __restrict__ ut,
                                                        const float2* __restrict__ KfP,
                                                        float* __restrict__ yt) {
    __shared__ float2 sm[NFFT];  // 64 KB
    const int b = blockIdx.x >> 6;
    const int c = blockIdx.x & 63;
    const int h0 = 2 * c, h1 = 2 * c + 1;
    const int tid = threadIdx.x;
    const float* up0 = ut + ((size_t)b * HH + h0) * LL;
    const float* up1 = ut + ((size_t)b * HH + h1) * LL;
    const float inv8192 = 1.0f / 8192.0f;

    // fused load + head radix-2 DIF stage (upper half of input is zero)
    for (int i = tid; i < 4096; i += 1024) {
        float2 a = make_float2(up0[i], up1[i]);
        float2 w = twid((float)i * inv8192, -1.f);
        sm[i] = a;
        sm[i + 4096] = cmul(w, a);
    }
    __syncthreads();

    dif_f4<1024>(sm, 8192, tid, 1024, -1.f);
    dif_f4<256>(sm, 8192, tid, 1024, -1.f);
    dif_f4<64>(sm, 8192, tid, 1024, -1.f);
    dif_f4<16>(sm, 8192, tid, 1024, -1.f);
    dif_f4<4>(sm, 8192, tid, 1024, -1.f);
    dif_f4<1>(sm, 8192, tid, 1024, -1.f);

    // Pointwise in bitrev order; each thread-iteration owns conjugate pair (k, N-k).
    // K reads are linear in t (coalesced); only K[p] is needed (Hermitian identity).
    const float2* kf0 = KfP + (size_t)h0 * KSTR;
    const float2* kf1 = KfP + (size_t)h1 * KSTR;
    for (int t = tid; t <= 4096; t += 1024) {
        int kk = kkmap(t);
        bool self = (kk == 0) || (kk == 4096);
        int p = brev13(kk);
        int q = self ? p : brev13(NFFT - kk);
        float2 K0 = kf0[t];
        float2 K1 = kf1[t];
        float2 Zp = sm[p];
        float2 Zq = sm[q];
        float2 U0 = make_float2(0.5f * (Zp.x + Zq.x), 0.5f * (Zp.y - Zq.y));
        float2 U1 = make_float2(0.5f * (Zp.y + Zq.y), 0.5f * (Zq.x - Zp.x));
        float2 A = cmul(U0, K0);
        float2 C = cmul(U1, K1);
        sm[p] = make_float2(A.x - C.y, A.y + C.x);             // W[k]   = A + iC
        if (!self) sm[q] = make_float2(A.x + C.y, C.x - A.y);  // W[N-k] = conj(A - iC)
    }
    __syncthreads();

    dit_f4<1>(sm, 8192, tid, 1024, +1.f);
    dit_f4<4>(sm, 8192, tid, 1024, +1.f);
    dit_f4<16>(sm, 8192, tid, 1024, +1.f);
    dit_f4<64>(sm, 8192, tid, 1024, +1.f);
    dit_f4<256>(sm, 8192, tid, 1024, +1.f);
    dit_f4<1024>(sm, 8192, tid, 1024, +1.f);

    // fused tail radix-2 DIT stage + 1/N scale + store (only first 4096 samples kept)
    float* yp0 = yt + ((size_t)b * HH + h0) * LL;
    float* yp1 = yt + ((size_t)b * HH + h1) * LL;
    const float invN = 1.0f / (float)NFFT;
    for (int x = tid; x < 4096; x += 1024) {
        float2 w = twid((float)x * inv8192, +1.f);
        float2 a = sm[x];
        float2 bb = cmul(w, sm[x + 4096]);
        yp0[x] = (a.x + bb.x) * invN;
        yp1[x] = (a.y + bb.y) * invN;
    }
}

// Kernel D: transpose yt [B,H,L] -> y [B,L,H], add broadcast skip[b,l]
__global__ __launch_bounds__(256) void transpose_y_kernel(const float* __restrict__ yt,
                                                          const float* __restrict__ skip,
                                                          float* __restrict__ y) {
    __shared__ float tile[32][33];
    int b = blockIdx.z;
    int h0 = blockIdx.x * 32, l0 = blockIdx.y * 32;
    const float* ytp = yt + (size_t)b * HH * LL;
    const float* skp = skip + (size_t)b * LL;
    float* yp = y + (size_t)b * LL * HH;
    for (int i = threadIdx.y; i < 32; i += 8)
        tile[i][threadIdx.x] = ytp[(size_t)(h0 + i) * LL + l0 + threadIdx.x];
    __syncthreads();
    for (int i = threadIdx.y; i < 32; i += 8) {
        size_t idx = (size_t)(l0 + i) * HH + h0 + threadIdx.x;
        yp[idx] = tile[threadIdx.x][i] + skp[l0 + i];
    }
}

extern "C" void kernel_launch(void* const* d_in, const int* in_sizes, int n_in,
                              void* d_out, int out_size, void* d_ws, size_t ws_size,
                              hipStream_t stream) {
    const float* u = (const float*)d_in[0];
    const float* B_ri = (const float*)d_in[1];
    const float* C_ri = (const float*)d_in[2];
    const float* D = (const float*)d_in[3];
    const float* Lambda_ri = (const float*)d_in[4];
    const float* P_ri = (const float*)d_in[5];
    const float* step = (const float*)d_in[6];
    float* out = (float*)d_out;

    char* ws = (char*)d_ws;
    float2* KfP = (float2*)ws;                              // ~4.1 MB @ 0
    float* skip = (float*)(ws + (size_t)6 * 1024 * 1024);   // 128 KB @ 6 MB
    float* ut = (float*)(ws + (size_t)8 * 1024 * 1024);     // 16 MB @ 8 MB
    float* yt = (float*)(ws + (size_t)24 * 1024 * 1024);    // 16 MB @ 24 MB
    // at_g aliases yt: written by stage1, consumed by kfreq before conv writes yt.
    float2* at_g = (float2*)yt;                             // 4 MB

    stage1_kernel<<<dim3(CAU_BLOCKS + TRU_BLOCKS + SKP_BLOCKS), dim3(256), 0, stream>>>(
        u, B_ri, C_ri, D, Lambda_ri, P_ri, step, at_g, ut, skip);
    kfreq_kernel<<<dim3(HH), dim3(1024), 0, stream>>>(at_g, KfP);
    conv_fft_kernel<<<dim3(BB * HH / 2), dim3(1024), 0, stream>>>(ut, KfP, yt);
    transpose_y_kernel<<<dim3(HH / 32, LL / 32, BB), dim3(32, 8), 0, stream>>>(yt, skip, out);
}